// Round 8
// baseline (122.393 us; speedup 1.0000x reference)
//
#include <hip/hip_runtime.h>

#define F_IN 256
#define H_DIM 128

typedef short bf16x8 __attribute__((ext_vector_type(8)));
typedef float f32x4 __attribute__((ext_vector_type(4)));
typedef unsigned short ushort8 __attribute__((ext_vector_type(8)));

__device__ inline unsigned short f2bf(float f) {
    unsigned int u = __float_as_uint(f);
    u += 0x7fffu + ((u >> 16) & 1u);   // RNE
    return (unsigned short)(u >> 16);
}
__device__ inline float bf_lo(unsigned int u) { return __uint_as_float(u << 16); }
__device__ inline float bf_hi(unsigned int u) { return __uint_as_float(u & 0xffff0000u); }

// ---------------- K0: zero the used 8B of each 64B-padded dc slot (2 shards per node)
__global__ __launch_bounds__(256) void zero_dc_kernel(unsigned long long* __restrict__ dc, int n2) {
    int i = blockIdx.x * blockDim.x + threadIdx.x;
    if (i < n2) dc[(size_t)i << 3] = 0ULL;
}

// ---------------- K1: u64 atomic per edge into shard (e&1): hi32 = count, lo32 = fx weight sum.
// Returned hi32 = rank within (dst, shard) bucket.
__global__ __launch_bounds__(256) void deg_count_kernel(const int* __restrict__ ei,
                                                        const float* __restrict__ ew,
                                                        unsigned long long* __restrict__ dc,
                                                        int* __restrict__ rank, int E) {
    int e = blockIdx.x * blockDim.x + threadIdx.x;
    if (e < E) {
        int d = ei[(size_t)E + e];
        int sh = e & 1;
        unsigned int fx = (unsigned int)__float2uint_rn(ew[e] * 65536.0f);
        unsigned long long old =
            atomicAdd(&dc[((size_t)(d * 2 + sh)) << 3], (1ULL << 32) | (unsigned long long)fx);
        rank[e] = (int)(old >> 32);
    }
}

// ---------------- K2: unpack 2 shards -> count, count0, dinv; fused per-block sum -> bsum
__global__ __launch_bounds__(256) void unpack_bsum_kernel(const unsigned long long* __restrict__ dc,
                                                          int* __restrict__ count,
                                                          int* __restrict__ count0,
                                                          float* __restrict__ dinv,
                                                          int* __restrict__ bsum, int N) {
    __shared__ int ws[4];
    int tid = threadIdx.x, lane = tid & 63, w = tid >> 6;
    int i = blockIdx.x * 256 + tid;
    int c = 0;
    if (i < N) {
        unsigned long long v0 = dc[((size_t)(i * 2)) << 3];
        unsigned long long v1 = dc[((size_t)(i * 2 + 1)) << 3];
        int c0 = (int)(v0 >> 32);
        c = c0 + (int)(v1 >> 32);
        count[i] = c;
        count0[i] = c0;
        unsigned int fsum = (unsigned int)v0 + (unsigned int)v1;   // max ~2.6M, no overflow
        dinv[i] = rsqrtf((float)fsum * (1.0f / 65536.0f) + 1.0f);
    }
    int v = c;
#pragma unroll
    for (int off = 32; off; off >>= 1) v += __shfl_xor(v, off, 64);
    if (lane == 0) ws[w] = v;
    __syncthreads();
    if (tid == 0) bsum[blockIdx.x] = ws[0] + ws[1] + ws[2] + ws[3];
}

__global__ __launch_bounds__(256) void scan_bsum_kernel(int* __restrict__ bsum, int nb) {
    __shared__ int tmp[256];
    int tid = threadIdx.x;
    int orig = (tid < nb) ? bsum[tid] : 0;
    tmp[tid] = orig;
    __syncthreads();
    for (int off = 1; off < 256; off <<= 1) {
        int t = (tid >= off) ? tmp[tid - off] : 0;
        __syncthreads();
        tmp[tid] += t;
        __syncthreads();
    }
    if (tid < nb) bsum[tid] = tmp[tid] - orig;   // exclusive
}

// ---------------- per-block scan -> sc[i] = {start, count0}
__global__ __launch_bounds__(256) void scan_write_kernel(const int* __restrict__ count,
                                                         const int* __restrict__ count0,
                                                         const int* __restrict__ bsum,
                                                         int2* __restrict__ sc, int N) {
    __shared__ int ws[4];
    int tid = threadIdx.x, lane = tid & 63, w = tid >> 6;
    int i = blockIdx.x * 256 + tid;
    int v = (i < N) ? count[i] : 0;
    int s = v;
#pragma unroll
    for (int off = 1; off < 64; off <<= 1) {
        int t = __shfl_up(s, off, 64);
        if (lane >= off) s += t;
    }
    if (lane == 63) ws[w] = s;
    __syncthreads();
    int add = bsum[blockIdx.x];
    for (int k = 0; k < w; k++) add += ws[k];
    if (i < N) {
        int2 o; o.x = s - v + add; o.y = count0[i];
        sc[i] = o;
    }
}

// ---------------- bucket edges: pos = start[d] + shard_off + rank[e]; NO atomics
__global__ __launch_bounds__(256) void place_kernel(const int* __restrict__ ei,
                                                    const float* __restrict__ ew,
                                                    const int2* __restrict__ sc,
                                                    const int* __restrict__ rank,
                                                    int2* __restrict__ sedge, int E) {
    int e = blockIdx.x * blockDim.x + threadIdx.x;
    if (e < E) {
        int s = ei[e];
        int d = ei[(size_t)E + e];
        int2 scd = sc[d];
        int pos = scd.x + ((e & 1) ? scd.y : 0) + rank[e];
        int2 p; p.x = s; p.y = __float_as_int(ew[e]);
        sedge[pos] = p;
    }
}

// ---------------- MFMA GEMM: xs(bf16) = (x @ W^T) * dinv[row]; W converted in-staging
__global__ __launch_bounds__(256) void gemm_mfma_kernel(const float* __restrict__ x,
                                                        const float* __restrict__ W,
                                                        const float* __restrict__ dinv,
                                                        unsigned short* __restrict__ xs, int N) {
    __shared__ unsigned short As[64 * 64];
    __shared__ unsigned short Bs[128 * 64];
    __shared__ float sdinv[64];
    const int tid = threadIdx.x;
    const int wv = tid >> 6, lane = tid & 63;
    const int block_row = blockIdx.x * 64;
    if (tid < 64) {
        int gr = block_row + tid;
        sdinv[tid] = (gr < N) ? dinv[gr] : 0.0f;
    }
    f32x4 acc[8] = {};

    for (int ks = 0; ks < 4; ks++) {
#pragma unroll
        for (int it = 0; it < 2; it++) {
            int gg = it * 256 + tid;
            int row = gg >> 3, g = gg & 7;
            int gr = block_row + row;
            float4 v0 = {0, 0, 0, 0}, v1 = {0, 0, 0, 0};
            if (gr < N) {
                const float4* p = (const float4*)&x[(size_t)gr * F_IN + ks * 64 + g * 8];
                v0 = p[0]; v1 = p[1];
            }
            ushort8 o;
            o[0] = f2bf(v0.x); o[1] = f2bf(v0.y); o[2] = f2bf(v0.z); o[3] = f2bf(v0.w);
            o[4] = f2bf(v1.x); o[5] = f2bf(v1.y); o[6] = f2bf(v1.z); o[7] = f2bf(v1.w);
            int slot = g ^ (row & 7);
            *(ushort8*)&As[row * 64 + slot * 8] = o;
        }
#pragma unroll
        for (int it = 0; it < 4; it++) {
            int gg = it * 256 + tid;
            int col = gg >> 3, g = gg & 7;
            const float4* p = (const float4*)&W[(size_t)col * F_IN + ks * 64 + g * 8];
            float4 v0 = p[0], v1 = p[1];
            ushort8 o;
            o[0] = f2bf(v0.x); o[1] = f2bf(v0.y); o[2] = f2bf(v0.z); o[3] = f2bf(v0.w);
            o[4] = f2bf(v1.x); o[5] = f2bf(v1.y); o[6] = f2bf(v1.z); o[7] = f2bf(v1.w);
            int slot = g ^ (col & 7);
            *(ushort8*)&Bs[col * 64 + slot * 8] = o;
        }
        __syncthreads();
        {
            int lrow = wv * 16 + (lane & 15);
            int lgrp = lane >> 4;
#pragma unroll
            for (int c = 0; c < 2; c++) {
                int sA = (c * 4 + lgrp) ^ (lrow & 7);
                bf16x8 a = *(bf16x8*)&As[lrow * 64 + sA * 8];
#pragma unroll
                for (int j = 0; j < 8; j++) {
                    int col = j * 16 + (lane & 15);
                    int sB = (c * 4 + lgrp) ^ (col & 7);
                    bf16x8 bfr = *(bf16x8*)&Bs[col * 64 + sB * 8];
                    acc[j] = __builtin_amdgcn_mfma_f32_16x16x32_bf16(a, bfr, acc[j], 0, 0, 0);
                }
            }
        }
        __syncthreads();
    }

    const int lc = lane & 15;
#pragma unroll
    for (int j = 0; j < 8; j++) {
#pragma unroll
        for (int r = 0; r < 4; r++) {
            int lrow = wv * 16 + (lane >> 4) * 4 + r;
            int grow = block_row + lrow;
            if (grow < N) {
                float v = acc[j][r] * sdinv[lrow];
                xs[(size_t)grow * H_DIM + j * 16 + lc] = f2bf(v);
            }
        }
    }
}

// ---------------- one wave per TWO dst rows (contiguous sedge range, masked A/B accumulate)
__global__ __launch_bounds__(256) void gather_out_kernel(const int2* __restrict__ sc,
                                                         const int2* __restrict__ sedge,
                                                         const unsigned int* __restrict__ xs,
                                                         const float* __restrict__ dinv,
                                                         const float* __restrict__ b,
                                                         const float* __restrict__ Wl,
                                                         const float* __restrict__ bl,
                                                         float* __restrict__ out,
                                                         int N, int E) {
    int pair = (blockIdx.x * blockDim.x + threadIdx.x) >> 6;
    int lane = threadIdx.x & 63;
    int rA = pair * 2;
    if (rA >= N) return;
    int rB = rA + 1;
    bool hasB = (rB < N);

    int s0 = sc[rA].x;
    int s1 = (rA + 2 < N) ? sc[rA + 2].x : E;
    int sB = hasB ? sc[rB].x : E;   // wave-uniform A/B boundary

    unsigned int suA = xs[(size_t)rA * 64 + lane];   // self-loops (already *dinv[src])
    float axA = bf_lo(suA), ayA = bf_hi(suA);
    float axB = 0.0f, ayB = 0.0f;
    if (hasB) {
        unsigned int suB = xs[(size_t)rB * 64 + lane];
        axB = bf_lo(suB); ayB = bf_hi(suB);
    }

    for (int base = s0; base < s1; base += 64) {
        int idx = base + lane;
        int sl = 0; float wl = 0.0f;
        if (idx < s1) {
            int2 p = sedge[idx];
            sl = p.x; wl = __int_as_float(p.y);
        }
        int m = min(64, s1 - base);
        int k = 0;
        for (; k + 8 <= m; k += 8) {
            int i0 = __shfl(sl, k, 64),     i1 = __shfl(sl, k + 1, 64);
            int i2 = __shfl(sl, k + 2, 64), i3 = __shfl(sl, k + 3, 64);
            int i4 = __shfl(sl, k + 4, 64), i5 = __shfl(sl, k + 5, 64);
            int i6 = __shfl(sl, k + 6, 64), i7 = __shfl(sl, k + 7, 64);
            float w0 = __shfl(wl, k, 64),     w1 = __shfl(wl, k + 1, 64);
            float w2 = __shfl(wl, k + 2, 64), w3 = __shfl(wl, k + 3, 64);
            float w4 = __shfl(wl, k + 4, 64), w5 = __shfl(wl, k + 5, 64);
            float w6 = __shfl(wl, k + 6, 64), w7 = __shfl(wl, k + 7, 64);
            unsigned int u0 = xs[(size_t)i0 * 64 + lane];
            unsigned int u1 = xs[(size_t)i1 * 64 + lane];
            unsigned int u2 = xs[(size_t)i2 * 64 + lane];
            unsigned int u3 = xs[(size_t)i3 * 64 + lane];
            unsigned int u4 = xs[(size_t)i4 * 64 + lane];
            unsigned int u5 = xs[(size_t)i5 * 64 + lane];
            unsigned int u6 = xs[(size_t)i6 * 64 + lane];
            unsigned int u7 = xs[(size_t)i7 * 64 + lane];
            // wave-uniform row select per edge -> masked weights
            float a0 = (base + k + 0 < sB) ? w0 : 0.0f; float b0 = w0 - a0;
            float a1 = (base + k + 1 < sB) ? w1 : 0.0f; float b1 = w1 - a1;
            float a2 = (base + k + 2 < sB) ? w2 : 0.0f; float b2 = w2 - a2;
            float a3 = (base + k + 3 < sB) ? w3 : 0.0f; float b3 = w3 - a3;
            float a4 = (base + k + 4 < sB) ? w4 : 0.0f; float b4 = w4 - a4;
            float a5 = (base + k + 5 < sB) ? w5 : 0.0f; float b5 = w5 - a5;
            float a6 = (base + k + 6 < sB) ? w6 : 0.0f; float b6 = w6 - a6;
            float a7 = (base + k + 7 < sB) ? w7 : 0.0f; float b7 = w7 - a7;
            axA += a0 * bf_lo(u0) + a1 * bf_lo(u1) + a2 * bf_lo(u2) + a3 * bf_lo(u3)
                 + a4 * bf_lo(u4) + a5 * bf_lo(u5) + a6 * bf_lo(u6) + a7 * bf_lo(u7);
            ayA += a0 * bf_hi(u0) + a1 * bf_hi(u1) + a2 * bf_hi(u2) + a3 * bf_hi(u3)
                 + a4 * bf_hi(u4) + a5 * bf_hi(u5) + a6 * bf_hi(u6) + a7 * bf_hi(u7);
            axB += b0 * bf_lo(u0) + b1 * bf_lo(u1) + b2 * bf_lo(u2) + b3 * bf_lo(u3)
                 + b4 * bf_lo(u4) + b5 * bf_lo(u5) + b6 * bf_lo(u6) + b7 * bf_lo(u7);
            ayB += b0 * bf_hi(u0) + b1 * bf_hi(u1) + b2 * bf_hi(u2) + b3 * bf_hi(u3)
                 + b4 * bf_hi(u4) + b5 * bf_hi(u5) + b6 * bf_hi(u6) + b7 * bf_hi(u7);
        }
        for (; k < m; k++) {
            int i0 = __shfl(sl, k, 64);
            float w0 = __shfl(wl, k, 64);
            unsigned int u0 = xs[(size_t)i0 * 64 + lane];
            float a0 = (base + k < sB) ? w0 : 0.0f; float b0 = w0 - a0;
            axA += a0 * bf_lo(u0); ayA += a0 * bf_hi(u0);
            axB += b0 * bf_lo(u0); ayB += b0 * bf_hi(u0);
        }
    }

    float2 bb = ((const float2*)b)[lane];
    float2 w0 = ((const float2*)Wl)[lane];
    float2 w1 = ((const float2*)(Wl + H_DIM))[lane];

    float diA = dinv[rA];
    float r0 = fmaxf(axA * diA + bb.x, 0.0f);
    float r1 = fmaxf(ayA * diA + bb.y, 0.0f);
    float z0A = r0 * w0.x + r1 * w0.y;
    float z1A = r0 * w1.x + r1 * w1.y;

    float diB = hasB ? dinv[rB] : 0.0f;
    float q0 = fmaxf(axB * diB + bb.x, 0.0f);
    float q1 = fmaxf(ayB * diB + bb.y, 0.0f);
    float z0B = q0 * w0.x + q1 * w0.y;
    float z1B = q0 * w1.x + q1 * w1.y;

#pragma unroll
    for (int off = 32; off; off >>= 1) {
        z0A += __shfl_xor(z0A, off, 64);
        z1A += __shfl_xor(z1A, off, 64);
        z0B += __shfl_xor(z0B, off, 64);
        z1B += __shfl_xor(z1B, off, 64);
    }
    if (lane == 0) {
        float bl0 = bl[0], bl1 = bl[1];
        float2 oA;
        oA.x = 1.0f / (1.0f + expf(-(z0A + bl0)));
        oA.y = 1.0f / (1.0f + expf(-(z1A + bl1)));
        ((float2*)out)[rA] = oA;
        if (hasB) {
            float2 oB;
            oB.x = 1.0f / (1.0f + expf(-(z0B + bl0)));
            oB.y = 1.0f / (1.0f + expf(-(z1B + bl1)));
            ((float2*)out)[rB] = oB;
        }
    }
}

extern "C" void kernel_launch(void* const* d_in, const int* in_sizes, int n_in,
                              void* d_out, int out_size, void* d_ws, size_t ws_size,
                              hipStream_t stream) {
    const float* x  = (const float*)d_in[0];
    const int* ei   = (const int*)d_in[1];   // int32 on device
    const float* ew = (const float*)d_in[2];
    const float* W  = (const float*)d_in[3];
    const float* b  = (const float*)d_in[4];
    const float* Wl = (const float*)d_in[5];
    const float* bl = (const float*)d_in[6];
    float* out = (float*)d_out;

    const int N = in_sizes[0] / F_IN;   // 50000
    const int E = in_sizes[2];          // 800000
    const int nb = (N + 255) / 256;

    char* ws = (char*)d_ws;
    size_t off = 0;
    unsigned short* xs = (unsigned short*)(ws + off); off += (size_t)N * H_DIM * 2;        // 12.8 MB
    unsigned long long* dc = (unsigned long long*)(ws + off); off += (size_t)N * 2 * 64;   // 6.4 MB padded
    int* rank    = (int*)(ws + off);  off += (size_t)E * 4;                                // 3.2 MB
    int* count   = (int*)(ws + off);  off += (size_t)N * 4;
    int* count0  = (int*)(ws + off);  off += (size_t)N * 4;
    float* dinv  = (float*)(ws + off); off += (size_t)N * 4;
    int* bsum    = (int*)(ws + off);  off += 256 * 4;
    off = (off + 15) & ~(size_t)15;
    int2* sc     = (int2*)(ws + off); off += (size_t)N * 8;
    int2* sedge  = (int2*)(ws + off); off += (size_t)E * 8;                                // 6.4 MB

    zero_dc_kernel<<<(2 * N + 255) / 256, 256, 0, stream>>>(dc, 2 * N);
    deg_count_kernel<<<(E + 255) / 256, 256, 0, stream>>>(ei, ew, dc, rank, E);
    unpack_bsum_kernel<<<nb, 256, 0, stream>>>(dc, count, count0, dinv, bsum, N);
    scan_bsum_kernel<<<1, 256, 0, stream>>>(bsum, nb);
    scan_write_kernel<<<nb, 256, 0, stream>>>(count, count0, bsum, sc, N);
    place_kernel<<<(E + 255) / 256, 256, 0, stream>>>(ei, ew, sc, rank, sedge, E);

    gemm_mfma_kernel<<<(N + 63) / 64, 256, 0, stream>>>(x, W, dinv, xs, N);

    int pairs = (N + 1) / 2;
    long long gthreads = (long long)pairs * 64;
    gather_out_kernel<<<(int)((gthreads + 255) / 256), 256, 0, stream>>>(
        sc, sedge, (const unsigned int*)xs, dinv, b, Wl, bl, out, N, E);
}